// Round 3
// baseline (831.346 us; speedup 1.0000x reference)
//
#include <hip/hip_runtime.h>
#include <stdint.h>

#define OH 250
#define OW 250
#define NPTS (OH*OW)        // 62500
#define SEG 65536           // padded segment length (pow2 >= NPTS)
#define TILE2 2048          // LDS sort tile (256 thr x 8 records)
#define NSEG 4              // y batches only (x-side is mathematically dead)
#define D 147               // 3*7*7
#define CH 3
#define IMH 256
#define IMW 256
#define NITER 17            // ceil(log2(62500)) + 1, per reference
#define NT (NSEG*SEG)       // 262144 total records

typedef unsigned long long u64;
typedef unsigned int u32;

// workspace layout (bytes)
#define OFF_KEYS 0UL         // u64[4*65536] = 2,097,152
#define OFF_PAYL 2097152UL   // u32[4*65536] = 1,048,576
#define OFF_WTS  3145728UL   // double[4*147] = 4,704
#define OFF_SUMS 3150432UL   // u64[4]
#define WS_NEED  3150464UL

#define LPAD(i) ((i) + ((i) >> 5))   // +1 u32 per 32: conflict-free for stride-8 & xor-j patterns
#define LDSN (TILE2 + TILE2/32)      // 2112

struct Rec { u64 k; u32 p; };

__device__ __forceinline__ bool rgt(const Rec& a, const Rec& b) {
  return (a.k > b.k) || (a.k == b.k && a.p > b.p);
}
__device__ __forceinline__ void ce(Rec& a, Rec& b, bool asc) {
  bool sw = asc ? rgt(a, b) : rgt(b, a);
  if (sw) { Rec t = a; a = b; b = t; }
}
__device__ __forceinline__ u64 packd(double f) {
  u64 u = (u64)__double_as_longlong(f);
  return (u & 0x8000000000000000ULL) ? ~u : (u | 0x8000000000000000ULL);
}

// ---- in-register networks on a contiguous run of 8 (run base = 8*tid) ----
__device__ __forceinline__ void sort8_phase2(Rec* r) {  // kk=2: dir=((i&2)==0)
  ce(r[0], r[1], true); ce(r[2], r[3], false); ce(r[4], r[5], true); ce(r[6], r[7], false);
}
__device__ __forceinline__ void sort8_phase4(Rec* r) {  // kk=4: dir=((i&4)==0), j=2,1
  ce(r[0], r[2], true); ce(r[1], r[3], true); ce(r[4], r[6], false); ce(r[5], r[7], false);
  ce(r[0], r[1], true); ce(r[2], r[3], true); ce(r[4], r[5], false); ce(r[6], r[7], false);
}
__device__ __forceinline__ void merge8(Rec* r, bool asc) {  // j=4,2,1, uniform dir
  ce(r[0], r[4], asc); ce(r[1], r[5], asc); ce(r[2], r[6], asc); ce(r[3], r[7], asc);
  ce(r[0], r[2], asc); ce(r[1], r[3], asc); ce(r[4], r[6], asc); ce(r[5], r[7], asc);
  ce(r[0], r[1], asc); ce(r[2], r[3], asc); ce(r[4], r[5], asc); ce(r[6], r[7], asc);
}

__device__ __forceinline__ void lds_write8(Rec* r, int tid, u32* khi, u32* klo, u32* pay) {
  #pragma unroll
  for (int m = 0; m < 8; ++m) {
    int p = LPAD(8 * tid + m);
    khi[p] = (u32)(r[m].k >> 32); klo[p] = (u32)r[m].k; pay[p] = r[m].p;
  }
}

// one cross-thread compare-exchange step, stride 8 <= j <= TILE2/2
__device__ __forceinline__ void lds_step(Rec* r, int tid, int j, bool asc,
                                         u32* khi, u32* klo, u32* pay) {
  __syncthreads();                 // previous reads done before overwrite
  lds_write8(r, tid, khi, klo, pay);
  __syncthreads();
  #pragma unroll
  for (int m = 0; m < 8; ++m) {
    int idx = 8 * tid + m;
    int q = LPAD(idx ^ j);
    Rec o; o.k = ((u64)khi[q] << 32) | klo[q]; o.p = pay[q];
    bool lower = (idx & j) == 0;
    bool keepmin = (lower == asc);
    bool ogt = rgt(r[m], o);
    Rec mn = ogt ? o : r[m];
    Rec mx = ogt ? r[m] : o;
    r[m] = keepmin ? mn : mx;
  }
}

// ---- phases kk=2..2048 fused (register + LDS) ----
__global__ __launch_bounds__(256) void sort_lo(u64* __restrict__ keys, u32* __restrict__ payl) {
  __shared__ u32 khi[LDSN], klo[LDSN], pay[LDSN];
  int base = blockIdx.x * TILE2, tid = threadIdx.x;
  for (int t = tid; t < TILE2; t += 256) {
    u64 k = keys[base + t]; int p = LPAD(t);
    khi[p] = (u32)(k >> 32); klo[p] = (u32)k; pay[p] = payl[base + t];
  }
  __syncthreads();
  Rec r[8];
  #pragma unroll
  for (int m = 0; m < 8; ++m) {
    int p = LPAD(8 * tid + m);
    r[m].k = ((u64)khi[p] << 32) | klo[p]; r[m].p = pay[p];
  }
  int lgi = (base + 8 * tid) & (SEG - 1);
  sort8_phase2(r);
  sort8_phase4(r);
  merge8(r, (lgi & 8) == 0);
  for (int kk = 16; kk <= TILE2; kk <<= 1) {
    bool asc = (lgi & kk) == 0;          // uniform across the run for kk>=16
    for (int j = kk >> 1; j >= 8; j >>= 1) lds_step(r, tid, j, asc, khi, klo, pay);
    merge8(r, asc);
  }
  __syncthreads();
  lds_write8(r, tid, khi, klo, pay);
  __syncthreads();
  for (int t = tid; t < TILE2; t += 256) {
    int p = LPAD(t);
    keys[base + t] = ((u64)khi[p] << 32) | klo[p];
    payl[base + t] = pay[p];
  }
}

// ---- phase-kk tail: j=1024..1 fused ----
__global__ __launch_bounds__(256) void sort_tail(u64* __restrict__ keys, u32* __restrict__ payl, int kk) {
  __shared__ u32 khi[LDSN], klo[LDSN], pay[LDSN];
  int base = blockIdx.x * TILE2, tid = threadIdx.x;
  for (int t = tid; t < TILE2; t += 256) {
    u64 k = keys[base + t]; int p = LPAD(t);
    khi[p] = (u32)(k >> 32); klo[p] = (u32)k; pay[p] = payl[base + t];
  }
  __syncthreads();
  Rec r[8];
  #pragma unroll
  for (int m = 0; m < 8; ++m) {
    int p = LPAD(8 * tid + m);
    r[m].k = ((u64)khi[p] << 32) | klo[p]; r[m].p = pay[p];
  }
  int lgi = (base + 8 * tid) & (SEG - 1);
  bool asc = (lgi & kk) == 0;            // kk=65536 -> 0 -> ascending final phase
  for (int j = TILE2 >> 1; j >= 8; j >>= 1) lds_step(r, tid, j, asc, khi, klo, pay);
  merge8(r, asc);
  __syncthreads();
  lds_write8(r, tid, khi, klo, pay);
  __syncthreads();
  for (int t = tid; t < TILE2; t += 256) {
    int p = LPAD(t);
    keys[base + t] = ((u64)khi[p] << 32) | klo[p];
    payl[base + t] = pay[p];
  }
}

// ---- multi-stride global steps: strides JLO<<(S-1) .. JLO, all in registers ----
template<int S, int LOGJ>
__global__ __launch_bounds__(256) void bitonic_multi(u64* __restrict__ keys,
                                                     u32* __restrict__ payl, int kk) {
  const int JLO = 1 << LOGJ;
  int g = blockIdx.x * 256 + threadIdx.x;       // group id, NT>>S total
  int low = g & (JLO - 1);
  int high = (g >> LOGJ) << (LOGJ + S);
  int i0 = high | low;
  bool asc = (((i0 & (SEG - 1)) & kk) == 0);    // uniform across group (kk > top stride)
  Rec e[1 << S];
  #pragma unroll
  for (int m = 0; m < (1 << S); ++m) {
    int idx = i0 + (m << LOGJ);
    e[m].k = keys[idx]; e[m].p = payl[idx];
  }
  #pragma unroll
  for (int s = S - 1; s >= 0; --s)
    #pragma unroll
    for (int m = 0; m < (1 << S); ++m)
      if (!(m & (1 << s))) ce(e[m], e[m | (1 << s)], asc);
  #pragma unroll
  for (int m = 0; m < (1 << S); ++m) {
    int idx = i0 + (m << LOGJ);
    keys[idx] = e[m].k; payl[idx] = e[m].p;
  }
}

// ---- per-batch projection weights: rand / std(rand, ddof=1), f64 ----
__global__ __launch_bounds__(256) void wkern(const float* __restrict__ rnd,
                                             double* __restrict__ wts) {
  __shared__ double red[256];
  int b = blockIdx.x, t = threadIdx.x;
  double val = (t < D) ? (double)rnd[b * D + t] : 0.0;
  red[t] = val;
  __syncthreads();
  for (int s = 128; s > 0; s >>= 1) { if (t < s) red[t] += red[t + s]; __syncthreads(); }
  double mean = red[0] / (double)D;
  __syncthreads();
  double dv = (t < D) ? (val - mean) : 0.0;
  red[t] = dv * dv;
  __syncthreads();
  for (int s = 128; s > 0; s >>= 1) { if (t < s) red[t] += red[t + s]; __syncthreads(); }
  double stdv = sqrt(red[0] / (double)(D - 1));
  if (t < D) wts[b * D + t] = val / stdv;
}

// ---- pad fill + zero accumulators ----
__global__ void init_pad(u64* __restrict__ keys, u32* __restrict__ payl,
                         u64* __restrict__ sums) {
  int t = blockIdx.x * blockDim.x + threadIdx.x;
  if (t < 4) sums[t] = 0ULL;
  const int pad = SEG - NPTS;                 // 3036
  if (t < NSEG * pad) {
    int s = t / pad, r = t - s * pad;
    keys[(size_t)s * SEG + NPTS + r] = ~0ULL;
    payl[(size_t)s * SEG + NPTS + r] = 0xFFFFFFFFu;
  }
}

// ---- 3x7x7 correlation of y (f64 accumulate) -> (key, payload) ----
__global__ __launch_bounds__(256) void conv_kern(const float* __restrict__ y,
                                                 const double* __restrict__ wts,
                                                 u64* __restrict__ keys,
                                                 u32* __restrict__ payl) {
  __shared__ float tile[CH][22][22];
  __shared__ double w[D];
  int b = blockIdx.z;
  const float* in = y + (size_t)b * CH * IMH * IMW;
  int bi = blockIdx.y * 16, bj = blockIdx.x * 16;
  int tid = threadIdx.y * 16 + threadIdx.x;
  if (tid < D) w[tid] = wts[b * D + tid];
  for (int c = 0; c < CH; ++c)
    for (int t = tid; t < 22 * 22; t += 256) {
      int rr = t / 22, cc = t - rr * 22;
      int r = bi + rr, col = bj + cc;
      float v = 0.f;
      if (r < IMH && col < IMW) v = in[((size_t)c * IMH + r) * IMW + col];
      tile[c][rr][cc] = v;
    }
  __syncthreads();
  int i = bi + threadIdx.y, j = bj + threadIdx.x;
  if (i < OH && j < OW) {
    double acc = 0.0;
    #pragma unroll
    for (int c = 0; c < CH; ++c)
      #pragma unroll
      for (int ph = 0; ph < 7; ++ph)
        #pragma unroll
        for (int pw = 0; pw < 7; ++pw)
          acc = fma((double)tile[c][threadIdx.y + ph][threadIdx.x + pw],
                    w[c * 49 + ph * 7 + pw], acc);
    int n = i * OW + j;
    keys[(size_t)b * SEG + n] = packd(acc);
    payl[(size_t)b * SEG + n] = (u32)n;
  }
}

// ---- exact replica of reference bisect_left-on-unsorted + nearest; sum over v=0..N-1 ----
// (ai is a permutation, so summing over v in natural order is integer-exact identical)
__global__ __launch_bounds__(256) void loss_kern(const u32* __restrict__ payl,
                                                 u64* __restrict__ sums) {
  int b = blockIdx.y;
  int v = blockIdx.x * 256 + threadIdx.x;
  const u32* a = payl + (size_t)b * SEG;       // argsort of proj_y (first NPTS entries)
  long long term = 0;
  if (v < NPTS) {
    int lo = 0, hi = NPTS;
    #pragma unroll
    for (int it = 0; it < NITER; ++it) {
      int mid = (lo + hi) >> 1;
      int cm = mid > NPTS - 1 ? NPTS - 1 : mid;
      int am = (int)a[cm];
      bool go = lo < hi;
      if (go) {
        if (am < v) lo = mid + 1;
        else        hi = mid;
      }
    }
    int pi = lo - 1; if (pi < 0) pi = 0; if (pi > NPTS - 1) pi = NPTS - 1;
    int ci = lo;     if (ci > NPTS - 1) ci = NPTS - 1;
    int ap = (int)a[pi], aa = (int)a[ci];
    int d1 = v - ap; if (d1 < 0) d1 = -d1;
    int d2 = v - aa; if (d2 < 0) d2 = -d2;
    bool take_prev = (lo > 0) && ((lo == NPTS) || (d1 < d2));
    int nearest = take_prev ? ap : aa;
    long long d = (long long)(v - nearest);
    term = d * d;
  }
  for (int off = 32; off > 0; off >>= 1) term += __shfl_down(term, off, 64);
  __shared__ long long part[4];
  int lane = threadIdx.x & 63, wid = threadIdx.x >> 6;
  if (lane == 0) part[wid] = term;
  __syncthreads();
  if (threadIdx.x == 0) {
    long long tot = part[0] + part[1] + part[2] + part[3];
    atomicAdd(&sums[b], (u64)tot);
  }
}

__global__ void final_kern(const u64* __restrict__ sums, float* __restrict__ out) {
  if (threadIdx.x == 0 && blockIdx.x == 0) {
    double l = 0.0;
    for (int b = 0; b < 4; ++b) l += (double)(long long)sums[b] / (double)NPTS;
    out[0] = (float)(l / 4.0);
  }
}

__global__ void guard_kern(float* __restrict__ out) {
  if (threadIdx.x == 0 && blockIdx.x == 0) out[0] = 9.0e12f;
}

extern "C" void kernel_launch(void* const* d_in, const int* in_sizes, int n_in,
                              void* d_out, int out_size, void* d_ws, size_t ws_size,
                              hipStream_t stream) {
  (void)in_sizes; (void)n_in; (void)out_size;
  if (ws_size < WS_NEED) { guard_kern<<<1, 64, 0, stream>>>((float*)d_out); return; }
  const float* y   = (const float*)d_in[1];
  const float* rnd = (const float*)d_in[2];

  char* ws = (char*)d_ws;
  u64* keys   = (u64*)(ws + OFF_KEYS);
  u32* payl   = (u32*)(ws + OFF_PAYL);
  double* wts = (double*)(ws + OFF_WTS);
  u64* sums   = (u64*)(ws + OFF_SUMS);

  wkern<<<4, 256, 0, stream>>>(rnd, wts);
  init_pad<<<(NSEG * (SEG - NPTS) + 255) / 256, 256, 0, stream>>>(keys, payl, sums);
  conv_kern<<<dim3(16, 16, NSEG), dim3(16, 16), 0, stream>>>(y, wts, keys, payl);

  sort_lo<<<NT / TILE2, 256, 0, stream>>>(keys, payl);                 // phases 2..2048
  bitonic_multi<1, 11><<<NT / 2 / 256, 256, 0, stream>>>(keys, payl, 4096);
  sort_tail<<<NT / TILE2, 256, 0, stream>>>(keys, payl, 4096);
  bitonic_multi<2, 11><<<NT / 4 / 256, 256, 0, stream>>>(keys, payl, 8192);
  sort_tail<<<NT / TILE2, 256, 0, stream>>>(keys, payl, 8192);
  bitonic_multi<3, 11><<<NT / 8 / 256, 256, 0, stream>>>(keys, payl, 16384);
  sort_tail<<<NT / TILE2, 256, 0, stream>>>(keys, payl, 16384);
  bitonic_multi<4, 11><<<NT / 16 / 256, 256, 0, stream>>>(keys, payl, 32768);
  sort_tail<<<NT / TILE2, 256, 0, stream>>>(keys, payl, 32768);
  bitonic_multi<4, 12><<<NT / 16 / 256, 256, 0, stream>>>(keys, payl, 65536);  // j=32768..4096
  bitonic_multi<1, 11><<<NT / 2 / 256, 256, 0, stream>>>(keys, payl, 65536);   // j=2048
  sort_tail<<<NT / TILE2, 256, 0, stream>>>(keys, payl, 65536);

  loss_kern<<<dim3((NPTS + 255) / 256, 4), 256, 0, stream>>>(payl, sums);
  final_kern<<<1, 64, 0, stream>>>(sums, (float*)d_out);
}

// Round 4
// 182.839 us; speedup vs baseline: 4.5469x; 4.5469x over previous
//
#include <hip/hip_runtime.h>
#include <stdint.h>

#define OH 250
#define OW 250
#define NPTS (OH*OW)        // 62500
#define SEG 65536           // padded segment length (pow2 >= NPTS)
#define NSEG 4              // y batches only (x-side is mathematically dead; verified R2/R3)
#define D 147               // 3*7*7
#define CH 3
#define IMH 256
#define IMW 256
#define NITER 17            // ceil(log2(62500)) + 1, per reference
#define NT (NSEG*SEG)       // 262144 records

#define TL 1024             // LDS sort tile -> 256 blocks over 4 segments
#define LPAD(i) ((i) + ((i) >> 5))
#define LDSN (TL + (TL >> 5))   // 1056 u32 per array

typedef unsigned long long u64;
typedef unsigned int u32;

// workspace layout (bytes)
#define OFF_KEYS 0UL         // u64[4*65536] = 2,097,152
#define OFF_PAYL 2097152UL   // u32[4*65536] = 1,048,576
#define OFF_WTS  3145728UL   // double[4*147] = 4,704
#define OFF_SUMS 3150432UL   // u64[4]
#define WS_NEED  3150464UL

__device__ __forceinline__ u64 packd(double f) {
  u64 u = (u64)__double_as_longlong(f);
  return (u & 0x8000000000000000ULL) ? ~u : (u | 0x8000000000000000ULL);
}
__device__ __forceinline__ bool kgt(u64 ka, u32 pa, u64 kb, u32 pb) {
  return (ka > kb) || (ka == kb && pa > pb);
}

// ---- prep: blocks 0..3 compute weights (rand/std ddof=1, f64); rest fill sort pads ----
__global__ __launch_bounds__(256) void prep_kern(const float* __restrict__ rnd,
                                                 double* __restrict__ wts,
                                                 u64* __restrict__ keys,
                                                 u32* __restrict__ payl,
                                                 u64* __restrict__ sums) {
  int t = threadIdx.x;
  if (blockIdx.x < 4) {
    __shared__ double red[256];
    int b = blockIdx.x;
    double val = (t < D) ? (double)rnd[b * D + t] : 0.0;
    red[t] = val;
    __syncthreads();
    for (int s = 128; s > 0; s >>= 1) { if (t < s) red[t] += red[t + s]; __syncthreads(); }
    double mean = red[0] / (double)D;
    __syncthreads();
    double dv = (t < D) ? (val - mean) : 0.0;
    red[t] = dv * dv;
    __syncthreads();
    for (int s = 128; s > 0; s >>= 1) { if (t < s) red[t] += red[t + s]; __syncthreads(); }
    double stdv = sqrt(red[0] / (double)(D - 1));
    if (t < D) wts[b * D + t] = val / stdv;
  } else {
    int g = (blockIdx.x - 4) * 256 + t;
    if (g < 4) sums[g] = 0ULL;
    const int pad = SEG - NPTS;                 // 3036
    if (g < NSEG * pad) {
      int s = g / pad, r = g - s * pad;
      keys[(size_t)s * SEG + NPTS + r] = ~0ULL;
      payl[(size_t)s * SEG + NPTS + r] = 0xFFFFFFFFu;
    }
  }
}

// ---- 3x7x7 correlation of y (f64 accumulate) -> (key, payload) ----
__global__ __launch_bounds__(256) void conv_kern(const float* __restrict__ y,
                                                 const double* __restrict__ wts,
                                                 u64* __restrict__ keys,
                                                 u32* __restrict__ payl) {
  __shared__ float tile[CH][22][22];
  __shared__ double w[D];
  int b = blockIdx.z;
  const float* in = y + (size_t)b * CH * IMH * IMW;
  int bi = blockIdx.y * 16, bj = blockIdx.x * 16;
  int tid = threadIdx.y * 16 + threadIdx.x;
  if (tid < D) w[tid] = wts[b * D + tid];
  for (int c = 0; c < CH; ++c)
    for (int t = tid; t < 22 * 22; t += 256) {
      int rr = t / 22, cc = t - rr * 22;
      int r = bi + rr, col = bj + cc;
      float v = 0.f;
      if (r < IMH && col < IMW) v = in[((size_t)c * IMH + r) * IMW + col];
      tile[c][rr][cc] = v;
    }
  __syncthreads();
  int i = bi + threadIdx.y, j = bj + threadIdx.x;
  if (i < OH && j < OW) {
    double acc = 0.0;
    #pragma unroll
    for (int c = 0; c < CH; ++c)
      #pragma unroll
      for (int ph = 0; ph < 7; ++ph)
        #pragma unroll
        for (int pw = 0; pw < 7; ++pw)
          acc = fma((double)tile[c][threadIdx.y + ph][threadIdx.x + pw],
                    w[c * 49 + ph * 7 + pw], acc);
    int n = i * OW + j;
    keys[(size_t)b * SEG + n] = packd(acc);
    payl[(size_t)b * SEG + n] = (u32)n;
  }
}

// ---- one LDS compare-exchange sweep body (scalar per thread, pair p=tid) ----
__device__ __forceinline__ void lds_sweep(int base, int tid, int j, int k,
                                          u32* khi, u32* klo, u32* pay) {
  __syncthreads();
  int i = ((tid & ~(j - 1)) << 1) | (tid & (j - 1));
  int l = i | j;
  int gi = (base + i) & (SEG - 1);
  bool asc = (gi & k) == 0;
  int qi = LPAD(i), ql = LPAD(l);
  u64 ka = ((u64)khi[qi] << 32) | klo[qi]; u32 pa = pay[qi];
  u64 kb = ((u64)khi[ql] << 32) | klo[ql]; u32 pb = pay[ql];
  bool sw = asc ? kgt(ka, pa, kb, pb) : kgt(kb, pb, ka, pa);
  if (sw) {
    khi[qi] = (u32)(kb >> 32); klo[qi] = (u32)kb; pay[qi] = pb;
    khi[ql] = (u32)(ka >> 32); klo[ql] = (u32)ka; pay[ql] = pa;
  }
}

// ---- phases k=2..1024 fused, one 1024-elem tile per block, 512 threads ----
__global__ __launch_bounds__(512) void sort_lo(u64* __restrict__ keys, u32* __restrict__ payl) {
  __shared__ u32 khi[LDSN], klo[LDSN], pay[LDSN];
  int base = blockIdx.x * TL, tid = threadIdx.x;
  for (int t = tid; t < TL; t += 512) {
    u64 k = keys[base + t]; int q = LPAD(t);
    khi[q] = (u32)(k >> 32); klo[q] = (u32)k; pay[q] = payl[base + t];
  }
  for (int k = 2; k <= TL; k <<= 1)
    for (int j = k >> 1; j > 0; j >>= 1)
      lds_sweep(base, tid, j, k, khi, klo, pay);
  __syncthreads();
  for (int t = tid; t < TL; t += 512) {
    int q = LPAD(t);
    keys[base + t] = ((u64)khi[q] << 32) | klo[q];
    payl[base + t] = pay[q];
  }
}

// ---- phase-kk tail: j=512..1 fused ----
__global__ __launch_bounds__(512) void sort_tail(u64* __restrict__ keys,
                                                 u32* __restrict__ payl, int kk) {
  __shared__ u32 khi[LDSN], klo[LDSN], pay[LDSN];
  int base = blockIdx.x * TL, tid = threadIdx.x;
  for (int t = tid; t < TL; t += 512) {
    u64 k = keys[base + t]; int q = LPAD(t);
    khi[q] = (u32)(k >> 32); klo[q] = (u32)k; pay[q] = payl[base + t];
  }
  for (int j = TL >> 1; j > 0; j >>= 1)
    lds_sweep(base, tid, j, kk, khi, klo, pay);
  __syncthreads();
  for (int t = tid; t < TL; t += 512) {
    int q = LPAD(t);
    keys[base + t] = ((u64)khi[q] << 32) | klo[q];
    payl[base + t] = pay[q];
  }
}

// ---- multi-stride global steps: strides JLO<<(S-1) .. JLO in registers (max 8 recs) ----
template<int S, int LOGJ>
__global__ __launch_bounds__(256, 2) void multi_step(u64* __restrict__ keys,
                                                     u32* __restrict__ payl, int kk) {
  const int M = 1 << S, JLO = 1 << LOGJ;
  int g = blockIdx.x * 256 + threadIdx.x;       // group id, NT>>S total
  int i0 = ((g >> LOGJ) << (LOGJ + S)) | (g & (JLO - 1));
  bool asc = ((i0 & (SEG - 1) & kk) == 0);      // uniform across group (kk > top stride)
  u64 k[M]; u32 p[M];
  #pragma unroll
  for (int m = 0; m < M; ++m) {
    int idx = i0 + (m << LOGJ);
    k[m] = keys[idx]; p[m] = payl[idx];
  }
  #pragma unroll
  for (int s = S - 1; s >= 0; --s)
    #pragma unroll
    for (int m = 0; m < M; ++m)
      if (!(m & (1 << s))) {
        int n = m | (1 << s);
        bool sw = asc ? kgt(k[m], p[m], k[n], p[n]) : kgt(k[n], p[n], k[m], p[m]);
        if (sw) { u64 tk = k[m]; k[m] = k[n]; k[n] = tk;
                  u32 tp = p[m]; p[m] = p[n]; p[n] = tp; }
      }
  #pragma unroll
  for (int m = 0; m < M; ++m) {
    int idx = i0 + (m << LOGJ);
    keys[idx] = k[m]; payl[idx] = p[m];
  }
}

// ---- exact replica of reference bisect_left-on-unsorted + nearest; sum over v=0..N-1 ----
__global__ __launch_bounds__(256) void loss_kern(const u32* __restrict__ payl,
                                                 u64* __restrict__ sums) {
  int b = blockIdx.y;
  int v = blockIdx.x * 256 + threadIdx.x;
  const u32* a = payl + (size_t)b * SEG;       // argsort of proj_y (first NPTS entries)
  long long term = 0;
  if (v < NPTS) {
    int lo = 0, hi = NPTS;
    #pragma unroll
    for (int it = 0; it < NITER; ++it) {
      int mid = (lo + hi) >> 1;
      int cm = mid > NPTS - 1 ? NPTS - 1 : mid;
      int am = (int)a[cm];
      bool go = lo < hi;
      if (go) {
        if (am < v) lo = mid + 1;
        else        hi = mid;
      }
    }
    int pi = lo - 1; if (pi < 0) pi = 0; if (pi > NPTS - 1) pi = NPTS - 1;
    int ci = lo;     if (ci > NPTS - 1) ci = NPTS - 1;
    int ap = (int)a[pi], aa = (int)a[ci];
    int d1 = v - ap; if (d1 < 0) d1 = -d1;
    int d2 = v - aa; if (d2 < 0) d2 = -d2;
    bool take_prev = (lo > 0) && ((lo == NPTS) || (d1 < d2));
    int nearest = take_prev ? ap : aa;
    long long d = (long long)(v - nearest);
    term = d * d;
  }
  for (int off = 32; off > 0; off >>= 1) term += __shfl_down(term, off, 64);
  __shared__ long long part[4];
  int lane = threadIdx.x & 63, wid = threadIdx.x >> 6;
  if (lane == 0) part[wid] = term;
  __syncthreads();
  if (threadIdx.x == 0) {
    long long tot = part[0] + part[1] + part[2] + part[3];
    atomicAdd(&sums[b], (u64)tot);
  }
}

__global__ void final_kern(const u64* __restrict__ sums, float* __restrict__ out) {
  if (threadIdx.x == 0 && blockIdx.x == 0) {
    double l = 0.0;
    for (int b = 0; b < 4; ++b) l += (double)(long long)sums[b] / (double)NPTS;
    out[0] = (float)(l / 4.0);
  }
}

__global__ void guard_kern(float* __restrict__ out) {
  if (threadIdx.x == 0 && blockIdx.x == 0) out[0] = 9.0e12f;
}

extern "C" void kernel_launch(void* const* d_in, const int* in_sizes, int n_in,
                              void* d_out, int out_size, void* d_ws, size_t ws_size,
                              hipStream_t stream) {
  (void)in_sizes; (void)n_in; (void)out_size;
  if (ws_size < WS_NEED) { guard_kern<<<1, 64, 0, stream>>>((float*)d_out); return; }
  const float* y   = (const float*)d_in[1];
  const float* rnd = (const float*)d_in[2];

  char* ws = (char*)d_ws;
  u64* keys   = (u64*)(ws + OFF_KEYS);
  u32* payl   = (u32*)(ws + OFF_PAYL);
  double* wts = (double*)(ws + OFF_WTS);
  u64* sums   = (u64*)(ws + OFF_SUMS);

  prep_kern<<<52, 256, 0, stream>>>(rnd, wts, keys, payl, sums);
  conv_kern<<<dim3(16, 16, NSEG), dim3(16, 16), 0, stream>>>(y, wts, keys, payl);

  sort_lo<<<NT / TL, 512, 0, stream>>>(keys, payl);                    // phases 2..1024
  // phase 2048: j=1024 global, then 512..1 in LDS
  multi_step<1, 10><<<(NT >> 1) / 256, 256, 0, stream>>>(keys, payl, 2048);
  sort_tail<<<NT / TL, 512, 0, stream>>>(keys, payl, 2048);
  // phase 4096: j=2048,1024
  multi_step<2, 10><<<(NT >> 2) / 256, 256, 0, stream>>>(keys, payl, 4096);
  sort_tail<<<NT / TL, 512, 0, stream>>>(keys, payl, 4096);
  // phase 8192: j=4096,2048,1024
  multi_step<3, 10><<<(NT >> 3) / 256, 256, 0, stream>>>(keys, payl, 8192);
  sort_tail<<<NT / TL, 512, 0, stream>>>(keys, payl, 8192);
  // phase 16384: j=8192,4096,2048 then 1024
  multi_step<3, 11><<<(NT >> 3) / 256, 256, 0, stream>>>(keys, payl, 16384);
  multi_step<1, 10><<<(NT >> 1) / 256, 256, 0, stream>>>(keys, payl, 16384);
  sort_tail<<<NT / TL, 512, 0, stream>>>(keys, payl, 16384);
  // phase 32768: j=16384,8192,4096 then 2048,1024
  multi_step<3, 12><<<(NT >> 3) / 256, 256, 0, stream>>>(keys, payl, 32768);
  multi_step<2, 10><<<(NT >> 2) / 256, 256, 0, stream>>>(keys, payl, 32768);
  sort_tail<<<NT / TL, 512, 0, stream>>>(keys, payl, 32768);
  // phase 65536: j=32768,16384,8192 then 4096,2048,1024
  multi_step<3, 13><<<(NT >> 3) / 256, 256, 0, stream>>>(keys, payl, 65536);
  multi_step<3, 10><<<(NT >> 3) / 256, 256, 0, stream>>>(keys, payl, 65536);
  sort_tail<<<NT / TL, 512, 0, stream>>>(keys, payl, 65536);

  loss_kern<<<dim3((NPTS + 255) / 256, 4), 256, 0, stream>>>(payl, sums);
  final_kern<<<1, 64, 0, stream>>>(sums, (float*)d_out);
}

// Round 5
// 137.572 us; speedup vs baseline: 6.0430x; 1.3290x over previous
//
#include <hip/hip_runtime.h>
#include <stdint.h>

#define OH 250
#define OW 250
#define NPTS (OH*OW)        // 62500
#define NSEG 4              // y batches only (x-side is mathematically dead; verified R2-R4)
#define D 147               // 3*7*7
#define CH 3
#define IMH 256
#define IMW 256
#define NITER 17            // ceil(log2(62500)) + 1, per reference
#define NBUCK 4096
#define SIG0 12.124355652982141  // sqrt(147): projection stddev model (bucketing only)

typedef unsigned long long u64;
typedef unsigned int u32;

// workspace layout (bytes, all 8-aligned)
#define OFF_REC   0UL        // u64[4*62500] = 2,000,000
#define OFF_SREC  2000000UL  // u64[4*62500] = 2,000,000
#define OFF_A     4000000UL  // u32[4*62500] = 1,000,000
#define OFF_HIST  5000000UL  // u32[4*4096]  = 65,536
#define OFF_BASES 5065536UL  // u32[4*4097]  = 65,552
#define OFF_CURS  5131088UL  // u32[4*4096]  = 65,536
#define OFF_WTS   5196624UL  // double[4*147]= 4,704
#define OFF_SUMS  5201328UL  // u64[4]       = 32
#define WS_NEED   5201360UL

__device__ __forceinline__ u64 packd(double f) {
  u64 u = (u64)__double_as_longlong(f);
  return (u & 0x8000000000000000ULL) ? ~u : (u | 0x8000000000000000ULL);
}

// bucket from the 47-bit-truncated transformed key (identical in conv & scatter;
// monotone non-decreasing with key order)
__device__ __forceinline__ int bucket_of(u64 rec) {
  u64 t = rec & ~0x1FFFFULL;                    // truncated transformed key
  u64 bits = (t & 0x8000000000000000ULL) ? (t & 0x7FFFFFFFFFFFFFFFULL) : ~t;
  double v = __longlong_as_double((long long)bits);
  double z = (v + 4.0 * SIG0) * ((double)NBUCK / (8.0 * SIG0));
  int b = (z <= 0.0) ? 0 : (int)z;              // trunc == floor for z>0
  if (b > NBUCK - 1) b = NBUCK - 1;
  return b;
}

// ---- prep: blocks 0..3 weights (rand/std ddof=1, f64); blocks 4..67 zero hist/sums ----
__global__ __launch_bounds__(256) void prep_kern(const float* __restrict__ rnd,
                                                 double* __restrict__ wts,
                                                 u32* __restrict__ hist,
                                                 u64* __restrict__ sums) {
  int t = threadIdx.x;
  if (blockIdx.x < 4) {
    __shared__ double red[256];
    int b = blockIdx.x;
    double val = (t < D) ? (double)rnd[b * D + t] : 0.0;
    red[t] = val;
    __syncthreads();
    for (int s = 128; s > 0; s >>= 1) { if (t < s) red[t] += red[t + s]; __syncthreads(); }
    double mean = red[0] / (double)D;
    __syncthreads();
    double dv = (t < D) ? (val - mean) : 0.0;
    red[t] = dv * dv;
    __syncthreads();
    for (int s = 128; s > 0; s >>= 1) { if (t < s) red[t] += red[t + s]; __syncthreads(); }
    double stdv = sqrt(red[0] / (double)(D - 1));
    if (t < D) wts[b * D + t] = val / stdv;
  } else {
    int g = (blockIdx.x - 4) * 256 + t;         // 0..16383
    if (g < NSEG * NBUCK) hist[g] = 0u;
    if (g < 4) sums[g] = 0ULL;
  }
}

// ---- 3x7x7 correlation of y (f64) -> u64 record (key47|idx17) + fused bucket histogram ----
__global__ __launch_bounds__(256) void conv_kern(const float* __restrict__ y,
                                                 const double* __restrict__ wts,
                                                 u64* __restrict__ recs,
                                                 u32* __restrict__ hist) {
  __shared__ float tile[CH][22][22];
  __shared__ double w[D];
  __shared__ u32 lh[NBUCK];
  int b = blockIdx.z;
  const float* in = y + (size_t)b * CH * IMH * IMW;
  int bi = blockIdx.y * 16, bj = blockIdx.x * 16;
  int tid = threadIdx.y * 16 + threadIdx.x;
  for (int k = tid; k < NBUCK; k += 256) lh[k] = 0u;
  if (tid < D) w[tid] = wts[b * D + tid];
  for (int c = 0; c < CH; ++c)
    for (int t = tid; t < 22 * 22; t += 256) {
      int rr = t / 22, cc = t - rr * 22;
      int r = bi + rr, col = bj + cc;
      float v = 0.f;
      if (r < IMH && col < IMW) v = in[((size_t)c * IMH + r) * IMW + col];
      tile[c][rr][cc] = v;
    }
  __syncthreads();
  int i = bi + threadIdx.y, j = bj + threadIdx.x;
  if (i < OH && j < OW) {
    double acc = 0.0;
    #pragma unroll
    for (int c = 0; c < CH; ++c)
      #pragma unroll
      for (int ph = 0; ph < 7; ++ph)
        #pragma unroll
        for (int pw = 0; pw < 7; ++pw)
          acc = fma((double)tile[c][threadIdx.y + ph][threadIdx.x + pw],
                    w[c * 49 + ph * 7 + pw], acc);
    int n = i * OW + j;
    u64 rec = (packd(acc) & ~0x1FFFFULL) | (u64)(u32)n;
    recs[(size_t)b * NPTS + n] = rec;
    atomicAdd(&lh[bucket_of(rec)], 1u);
  }
  __syncthreads();
  for (int k = tid; k < NBUCK; k += 256) {
    u32 c = lh[k];
    if (c) atomicAdd(&hist[b * NBUCK + k], c);
  }
}

// ---- per-segment exclusive scan of 4096 bucket counts -> bases, cursors ----
__global__ __launch_bounds__(1024) void scan_kern(const u32* __restrict__ hist,
                                                  u32* __restrict__ bases,
                                                  u32* __restrict__ curs) {
  __shared__ u32 part[1024];
  int seg = blockIdx.x, t = threadIdx.x;
  u32 c[4];
  #pragma unroll
  for (int m = 0; m < 4; ++m) c[m] = hist[seg * NBUCK + 4 * t + m];
  u32 s = c[0] + c[1] + c[2] + c[3];
  part[t] = s;
  __syncthreads();
  for (int off = 1; off < 1024; off <<= 1) {
    u32 v = (t >= off) ? part[t - off] : 0u;
    __syncthreads();
    part[t] += v;
    __syncthreads();
  }
  u32 ex = part[t] - s;                          // exclusive prefix for this thread's 4 bins
  #pragma unroll
  for (int m = 0; m < 4; ++m) {
    bases[seg * (NBUCK + 1) + 4 * t + m] = ex;
    curs[seg * NBUCK + 4 * t + m] = ex;
    ex += c[m];
  }
  if (t == 1023) bases[seg * (NBUCK + 1) + NBUCK] = ex;   // == NPTS
}

// ---- unstable scatter into bucket ranges (order fixed later by exact rank sort) ----
__global__ __launch_bounds__(256) void scatter_kern(const u64* __restrict__ recs,
                                                    u32* __restrict__ curs,
                                                    u64* __restrict__ srec) {
  int seg = blockIdx.y;
  int e = blockIdx.x * 256 + threadIdx.x;
  if (e < NPTS) {
    u64 rec = recs[(size_t)seg * NPTS + e];
    int bk = bucket_of(rec);
    u32 pos = atomicAdd(&curs[seg * NBUCK + bk], 1u);
    srec[(size_t)seg * NPTS + pos] = rec;
  }
}

// ---- one wave per bucket: exact rank sort (records all distinct), write argsort idx ----
__global__ __launch_bounds__(512) void bsort_kern(const u64* __restrict__ srec,
                                                  const u32* __restrict__ bases,
                                                  u32* __restrict__ a) {
  __shared__ u64 buf[8][512];
  int wid = threadIdx.x >> 6, lane = threadIdx.x & 63;
  int w = blockIdx.x * 8 + wid;                  // 16384 waves total
  int seg = w >> 12, bk = w & (NBUCK - 1);
  u32 b0 = bases[seg * (NBUCK + 1) + bk];
  u32 b1 = bases[seg * (NBUCK + 1) + bk + 1];
  int n = (int)(b1 - b0);
  const u64* src = srec + (size_t)seg * NPTS + b0;
  u32* dst = a + (size_t)seg * NPTS + b0;
  bool uselds = (n <= 512);
  if (uselds) for (int i = lane; i < n; i += 64) buf[wid][i] = src[i];
  __syncthreads();
  if (uselds) {
    for (int i = lane; i < n; i += 64) {
      u64 x = buf[wid][i];
      int r = 0;
      for (int j = 0; j < n; ++j) r += (buf[wid][j] < x);   // broadcast read, conflict-free
      dst[r] = (u32)(x & 0x1FFFFULL);
    }
  } else {                                        // safety fallback, exact (never expected)
    for (int i = lane; i < n; i += 64) {
      u64 x = src[i];
      int r = 0;
      for (int j = 0; j < n; ++j) r += (src[j] < x);
      dst[r] = (u32)(x & 0x1FFFFULL);
    }
  }
}

// ---- exact replica of reference bisect_left-on-unsorted + nearest; sum over v=0..N-1 ----
// (ai is a permutation, so the x-side argsort is mathematically dead — verified R2-R4)
__global__ __launch_bounds__(256) void loss_kern(const u32* __restrict__ a_all,
                                                 u64* __restrict__ sums) {
  int b = blockIdx.y;
  int v = blockIdx.x * 256 + threadIdx.x;
  const u32* a = a_all + (size_t)b * NPTS;       // argsort of proj_y
  long long term = 0;
  if (v < NPTS) {
    int lo = 0, hi = NPTS;
    #pragma unroll
    for (int it = 0; it < NITER; ++it) {
      int mid = (lo + hi) >> 1;
      int cm = mid > NPTS - 1 ? NPTS - 1 : mid;
      int am = (int)a[cm];
      bool go = lo < hi;
      if (go) {
        if (am < v) lo = mid + 1;
        else        hi = mid;
      }
    }
    int pi = lo - 1; if (pi < 0) pi = 0; if (pi > NPTS - 1) pi = NPTS - 1;
    int ci = lo;     if (ci > NPTS - 1) ci = NPTS - 1;
    int ap = (int)a[pi], aa = (int)a[ci];
    int d1 = v - ap; if (d1 < 0) d1 = -d1;
    int d2 = v - aa; if (d2 < 0) d2 = -d2;
    bool take_prev = (lo > 0) && ((lo == NPTS) || (d1 < d2));
    int nearest = take_prev ? ap : aa;
    long long d = (long long)(v - nearest);
    term = d * d;
  }
  for (int off = 32; off > 0; off >>= 1) term += __shfl_down(term, off, 64);
  __shared__ long long part[4];
  int lane = threadIdx.x & 63, wid = threadIdx.x >> 6;
  if (lane == 0) part[wid] = term;
  __syncthreads();
  if (threadIdx.x == 0) {
    long long tot = part[0] + part[1] + part[2] + part[3];
    atomicAdd(&sums[b], (u64)tot);
  }
}

__global__ void final_kern(const u64* __restrict__ sums, float* __restrict__ out) {
  if (threadIdx.x == 0 && blockIdx.x == 0) {
    double l = 0.0;
    for (int b = 0; b < 4; ++b) l += (double)(long long)sums[b] / (double)NPTS;
    out[0] = (float)(l / 4.0);
  }
}

__global__ void guard_kern(float* __restrict__ out) {
  if (threadIdx.x == 0 && blockIdx.x == 0) out[0] = 9.0e12f;
}

extern "C" void kernel_launch(void* const* d_in, const int* in_sizes, int n_in,
                              void* d_out, int out_size, void* d_ws, size_t ws_size,
                              hipStream_t stream) {
  (void)in_sizes; (void)n_in; (void)out_size;
  if (ws_size < WS_NEED) { guard_kern<<<1, 64, 0, stream>>>((float*)d_out); return; }
  const float* y   = (const float*)d_in[1];
  const float* rnd = (const float*)d_in[2];

  char* ws = (char*)d_ws;
  u64* recs   = (u64*)(ws + OFF_REC);
  u64* srec   = (u64*)(ws + OFF_SREC);
  u32* a      = (u32*)(ws + OFF_A);
  u32* hist   = (u32*)(ws + OFF_HIST);
  u32* bases  = (u32*)(ws + OFF_BASES);
  u32* curs   = (u32*)(ws + OFF_CURS);
  double* wts = (double*)(ws + OFF_WTS);
  u64* sums   = (u64*)(ws + OFF_SUMS);

  prep_kern<<<68, 256, 0, stream>>>(rnd, wts, hist, sums);
  conv_kern<<<dim3(16, 16, NSEG), dim3(16, 16), 0, stream>>>(y, wts, recs, hist);
  scan_kern<<<NSEG, 1024, 0, stream>>>(hist, bases, curs);
  scatter_kern<<<dim3((NPTS + 255) / 256, NSEG), 256, 0, stream>>>(recs, curs, srec);
  bsort_kern<<<NSEG * NBUCK / 8, 512, 0, stream>>>(srec, bases, a);
  loss_kern<<<dim3((NPTS + 255) / 256, NSEG), 256, 0, stream>>>(a, sums);
  final_kern<<<1, 64, 0, stream>>>(sums, (float*)d_out);
}